// Round 9
// baseline (158.675 us; speedup 1.0000x reference)
//
#include <hip/hip_runtime.h>
#include <hip/hip_bf16.h>

#define N_PTS 50000
#define H_NB 32
#define K_KP 15
#define C_IN 64
#define C_OUT 128
#define M_TILE 16
#define PPW 4            // points per wave (4 waves)
#define KC 960           // K_KP * C_IN
#define WFS 968          // wf_lds row stride (bf16 elems), rows 16B-aligned
#define XG_SUB 68        // h-subtile stride (elems): 64 + 4 -> lq spreads banks
#define XG_PLANE 552     // ct-plane stride (elems), mult of 8
#define XG_WAVE (4*XG_PLANE)
#define BN_EPS 1e-5f
#define SLOPE 0.2f

typedef __attribute__((ext_vector_type(8))) __bf16 bf16x8;
typedef __attribute__((ext_vector_type(8))) unsigned short ushort8;
typedef __attribute__((ext_vector_type(4))) float f32x4;

__device__ __forceinline__ unsigned short bfbits(float f){
  return __builtin_bit_cast(unsigned short, (__bf16)f);
}

// ---- prep: W[kc][d] f32 -> Wt[d][kc] bf16 (LDS tile transpose); block(0,0) zeros stats ----
__global__ __launch_bounds__(256) void prep_kernel(const float* __restrict__ W,
                                                   unsigned short* __restrict__ Wt,
                                                   float* __restrict__ stats){
  __shared__ float tile[32][33];
  if (blockIdx.x == 0 && blockIdx.y == 0 && threadIdx.x < 2*C_OUT)
    stats[threadIdx.x] = 0.f;
  const int kc0 = blockIdx.x * 32, d0 = blockIdx.y * 32;
  const int r = threadIdx.x >> 5, c = threadIdx.x & 31;
  #pragma unroll
  for (int rr = 0; rr < 4; ++rr) {
    int row = rr*8 + r;
    tile[row][c] = W[(size_t)(kc0+row)*C_OUT + d0 + c];
  }
  __syncthreads();
  #pragma unroll
  for (int rr = 0; rr < 4; ++rr) {
    int dr = rr*8 + r;
    Wt[(size_t)(d0+dr)*KC + kc0 + c] = bfbits(tile[c][dr]);
  }
}

__global__ __launch_bounds__(256, 3) void kpconv_kernel(
    const float* __restrict__ points,
    const float* __restrict__ x,
    const int*   __restrict__ neighbors,
    const float* __restrict__ kpts,
    const unsigned short* __restrict__ Wt,
    float* __restrict__ out_pre,
    float* __restrict__ stats)
{
  // LDS: 30976 + 17664 + 512 + 512 = 49664 B -> 3 blocks/CU (12 waves)
  __shared__ unsigned short wf_lds[M_TILE * WFS];
  __shared__ unsigned short xg[4 * XG_WAVE];   // per-wave gathered-x, subtiled
  __shared__ float sh_sum[C_OUT];
  __shared__ float sh_sq[C_OUT];

  const int tid  = threadIdx.x;
  const int w    = tid >> 6;
  const int lane = tid & 63;
  const int l15  = lane & 15;
  const int lq   = lane >> 4;
  const int base = blockIdx.x * M_TILE;   // 50000 = 16*3125, exact

  // this lane's kernel point (m = l15); m==15 -> influence forced to 0 (far sentinel)
  float kqx, kqy, kqz;
  if (l15 < K_KP) { kqx = kpts[l15*3+0]; kqy = kpts[l15*3+1]; kqz = kpts[l15*3+2]; }
  else            { kqx = 1e3f; kqy = 0.f; kqz = 0.f; }

  unsigned short* xgw = &xg[w * XG_WAVE];

  // ---------------- Phase A: per-point MFMA  wf[k][c] = infl[k][h] @ x_g[h][c] ----------------
  {
    int   idx_c, idx_n = 0, idx_nn = 0;
    float pcx, pcy, pcz, pnx = 0, pny = 0, pnz = 0;
    float ccx, ccy, ccz, cnx = 0, cny = 0, cnz = 0, c2x = 0, c2y = 0, c2z = 0;
    float4 xr[8];

    // prologue: point 0 fully issued, point 1 idx/center/npos issued
    {
      int n0 = base + w*PPW;
      idx_c = neighbors[n0*H_NB + (lane & 31)];
      ccx = points[n0*3+0]; ccy = points[n0*3+1]; ccz = points[n0*3+2];
      const float* pp = points + (size_t)idx_c*3;
      pcx = pp[0]; pcy = pp[1]; pcz = pp[2];
      #pragma unroll
      for (int it = 0; it < 8; ++it) {
        int h  = 4*it + lq;
        int nh = __shfl(idx_c, h);
        xr[it] = *(const float4*)&x[(size_t)nh*C_IN + 4*l15];
      }
      int n1 = n0 + 1;
      idx_n = neighbors[n1*H_NB + (lane & 31)];
      cnx = points[n1*3+0]; cny = points[n1*3+1]; cnz = points[n1*3+2];
      const float* pq = points + (size_t)idx_n*3;
      pnx = pq[0]; pny = pq[1]; pnz = pq[2];
    }

    #pragma unroll 1
    for (int p = 0; p < PPW; ++p) {
      const int mpt = w*PPW + p;

      // influence A-frag: lane holds infl(kernel-pt m=l15, h = lq*8+j)
      float rx = pcx - ccx, ry = pcy - ccy, rz = pcz - ccz;   // lanes 0-31 meaningful
      bf16x8 afrag;
      #pragma unroll
      for (int j = 0; j < 8; ++j) {
        int h = (lq << 3) + j;
        float dx = __shfl(rx, h) - kqx;
        float dy = __shfl(ry, h) - kqy;
        float dz = __shfl(rz, h) - kqz;
        float ss = dx*dx + dy*dy + dz*dz;
        float f  = 1.f - sqrtf(ss);
        f = f > 0.f ? f : 0.f;
        afrag[j] = (__bf16)f;
      }

      // stage current point's gathered x -> LDS (bf16, subtiled [ct][h>>2][h&3][c16])
      #pragma unroll
      for (int it = 0; it < 8; ++it) {
        float4 v = xr[it];
        unsigned lo = ((unsigned)bfbits(v.y) << 16) | bfbits(v.x);
        unsigned hi = ((unsigned)bfbits(v.w) << 16) | bfbits(v.z);
        int ei = XG_PLANE*(l15 >> 2) + XG_SUB*it + 16*lq + 4*(l15 & 3);
        uint2 val; val.x = lo; val.y = hi;
        *(uint2*)(xgw + ei) = val;
      }

      // issue next point's gather (1-deep pipeline)
      if (p + 1 < PPW) {
        #pragma unroll
        for (int it = 0; it < 8; ++it) {
          int h  = 4*it + lq;
          int nh = __shfl(idx_n, h);
          xr[it] = *(const float4*)&x[(size_t)nh*C_IN + 4*l15];
        }
      }
      if (p + 2 < PPW) {
        int n2 = base + w*PPW + p + 2;
        idx_nn = neighbors[n2*H_NB + (lane & 31)];
        c2x = points[n2*3+0]; c2y = points[n2*3+1]; c2z = points[n2*3+2];
      }

      // drain staging writes (wave-local cross-lane visibility)
      asm volatile("s_waitcnt lgkmcnt(0)" ::: "memory");

      // B-frags: lane wants xg[h = lq*8+j][c = ct*16 + l15]
      // elem = PLANE*ct + SUB*(2lq + (j>>2)) + 16*(j&3) + l15 -> banks spread, <=2-way
      ushort8 bbr[4];
      #pragma unroll
      for (int ct = 0; ct < 4; ++ct) {
        #pragma unroll
        for (int j = 0; j < 8; ++j) {
          bbr[ct][j] = xgw[XG_PLANE*ct + XG_SUB*(2*lq + (j>>2)) + 16*(j&3) + l15];
        }
      }

      f32x4 acc[4] = {{0,0,0,0},{0,0,0,0},{0,0,0,0},{0,0,0,0}};
      #pragma unroll
      for (int ct = 0; ct < 4; ++ct) {
        bf16x8 bv = __builtin_bit_cast(bf16x8, bbr[ct]);
        acc[ct] = __builtin_amdgcn_mfma_f32_16x16x32_bf16(afrag, bv, acc[ct], 0, 0, 0);
      }

      // writeback wf rows (C layout: k = 4*lq + r, c = ct*16 + l15), XOR-swizzled:
      // c' = (ct ^ lq)*16 + l15 spreads the lq-groups across banks (4-way -> none)
      #pragma unroll
      for (int ct = 0; ct < 4; ++ct) {
        #pragma unroll
        for (int r = 0; r < 4; ++r) {
          int k = 4*lq + r;
          if (k < K_KP)
            wf_lds[mpt*WFS + k*C_IN + ((ct ^ lq)*16) + l15] = bfbits(acc[ct][r]);
        }
      }

      // rotate pipeline registers; prefetch npos for the new "next" point
      if (p + 1 < PPW) {
        pcx = pnx; pcy = pny; pcz = pnz;
        ccx = cnx; ccy = cny; ccz = cnz;
        idx_c = idx_n; idx_n = idx_nn;
        cnx = c2x; cny = c2y; cnz = c2z;
        if (p + 2 < PPW) {
          const float* pq = points + (size_t)idx_n*3;
          pnx = pq[0]; pny = pq[1]; pnz = pq[2];
        }
      }
    }
  }

  __syncthreads();

  // ---------------- Phase B: out[16x128] = wf[16x960] @ Wt^T via MFMA ----------------
  const int wd = w;   // 4 waves -> 4 col-tiles of 32
  f32x4 b00{0,0,0,0}, b01{0,0,0,0};

  const unsigned short* arow  = &wf_lds[l15*WFS];
  const unsigned short* wrow0 = Wt + (size_t)(wd*32 + l15)*KC + lq*8;
  const unsigned short* wrow1 = wrow0 + (size_t)16*KC;

  #pragma unroll 6
  for (int ks = 0; ks < KC/32; ++ks) {
    // A-read undoes the writeback swizzle: k = ks>>1 -> XOR by (k>>2 & 3)<<4 on the c-offset
    int aoff = (ks*32 + lq*8) ^ ((((ks >> 1) >> 2) & 3) << 4);
    bf16x8 a0 = __builtin_bit_cast(bf16x8, *(const uint4*)(arow + aoff));
    bf16x8 w0 = __builtin_bit_cast(bf16x8, *(const uint4*)(wrow0 + ks*32));
    bf16x8 w1 = __builtin_bit_cast(bf16x8, *(const uint4*)(wrow1 + ks*32));
    b00 = __builtin_amdgcn_mfma_f32_16x16x32_bf16(a0, w0, b00, 0, 0, 0);
    b01 = __builtin_amdgcn_mfma_f32_16x16x32_bf16(a0, w1, b01, 0, 0, 0);
  }

  // ---------------- Epilogue: store pre-BN + per-block stats ----------------
  float s0 = 0.f, q0 = 0.f, s1 = 0.f, q1 = 0.f;
  const int dcol0 = wd*32 + l15;
  #pragma unroll
  for (int r = 0; r < 4; ++r) {
    int n = base + 4*lq + r;    // C/D: row = lq*4 + r
    float v0 = b00[r], v1 = b01[r];
    out_pre[(size_t)n*C_OUT + dcol0]      = v0;
    out_pre[(size_t)n*C_OUT + dcol0 + 16] = v1;
    s0 += v0; q0 += v0*v0;
    s1 += v1; q1 += v1*v1;
  }
  s0 += __shfl_xor(s0, 16); s0 += __shfl_xor(s0, 32);
  q0 += __shfl_xor(q0, 16); q0 += __shfl_xor(q0, 32);
  s1 += __shfl_xor(s1, 16); s1 += __shfl_xor(s1, 32);
  q1 += __shfl_xor(q1, 16); q1 += __shfl_xor(q1, 32);
  if (lane < 16) {               // each (wave, l15) owns 2 distinct columns
    sh_sum[wd*32 + lane]      = s0;
    sh_sum[wd*32 + 16 + lane] = s1;
    sh_sq [wd*32 + lane]      = q0;
    sh_sq [wd*32 + 16 + lane] = q1;
  }
  __syncthreads();
  if (tid < C_OUT) {
    atomicAdd(&stats[tid],         sh_sum[tid]);
    atomicAdd(&stats[C_OUT + tid], sh_sq[tid]);
  }
}

__global__ void finalize_kernel(const float* __restrict__ stats,
                                const float* __restrict__ gamma,
                                const float* __restrict__ beta,
                                float* __restrict__ sc_sh){
  int d = threadIdx.x;
  if (d < C_OUT) {
    float mean = stats[d] * (1.f/N_PTS);
    float var  = stats[C_OUT+d] * (1.f/N_PTS) - mean*mean;
    var = var > 0.f ? var : 0.f;
    float inv = rsqrtf(var + BN_EPS);
    float sc  = inv * gamma[d];
    sc_sh[d]        = sc;
    sc_sh[C_OUT+d]  = beta[d] - mean * sc;
  }
}

__global__ __launch_bounds__(256) void bn_lrelu_kernel(float* __restrict__ out,
                                                       const float* __restrict__ sc_sh){
  const int total4 = N_PTS*C_OUT/4;
  const float4* scp = (const float4*)sc_sh;
  const float4* shp = (const float4*)(sc_sh + C_OUT);
  float4* o4 = (float4*)out;
  for (int t = blockIdx.x*blockDim.x + threadIdx.x; t < total4; t += gridDim.x*blockDim.x) {
    int col4 = t & (C_OUT/4 - 1);
    float4 v = o4[t];
    float4 sc = scp[col4], sh = shp[col4];
    float y0 = v.x*sc.x + sh.x;
    float y1 = v.y*sc.y + sh.y;
    float y2 = v.z*sc.z + sh.z;
    float y3 = v.w*sc.w + sh.w;
    v.x = y0 > 0.f ? y0 : SLOPE*y0;
    v.y = y1 > 0.f ? y1 : SLOPE*y1;
    v.z = y2 > 0.f ? y2 : SLOPE*y2;
    v.w = y3 > 0.f ? y3 : SLOPE*y3;
    o4[t] = v;
  }
}

extern "C" void kernel_launch(void* const* d_in, const int* in_sizes, int n_in,
                              void* d_out, int out_size, void* d_ws, size_t ws_size,
                              hipStream_t stream) {
  const float* points    = (const float*)d_in[0];
  const float* x         = (const float*)d_in[1];
  const int*   neighbors = (const int*)d_in[2];
  const float* kpts      = (const float*)d_in[3];
  const float* weights   = (const float*)d_in[4];
  const float* gamma     = (const float*)d_in[5];
  const float* beta      = (const float*)d_in[6];
  float* out = (float*)d_out;
  float* ws  = (float*)d_ws;
  // ws layout: [0..255] stats, [256..511] scale/shift, [512..] Wt bf16 (960*128*2 B)
  unsigned short* Wt = (unsigned short*)(ws + 2*C_OUT + 2*C_OUT);

  hipLaunchKernelGGL(prep_kernel, dim3(KC/32, C_OUT/32), dim3(256), 0, stream,
                     weights, Wt, ws);
  const int nblocks = N_PTS / M_TILE;   // 3125 exact
  hipLaunchKernelGGL(kpconv_kernel, dim3(nblocks), dim3(256), 0, stream,
                     points, x, neighbors, kpts, Wt, out, ws);
  hipLaunchKernelGGL(finalize_kernel, dim3(1), dim3(128), 0, stream, ws, gamma, beta, ws + 2*C_OUT);
  hipLaunchKernelGGL(bn_lrelu_kernel, dim3(2048), dim3(256), 0, stream, out, ws + 2*C_OUT);
}